// Round 1
// baseline (397.400 us; speedup 1.0000x reference)
//
#include <hip/hip_runtime.h>
#include <math.h>

#define NQ 12
#define NSTATE 4096
#define NTHREADS 256
#define NL 3

// ---------------------------------------------------------------------------
// Setup kernel: build the 36 fused 1q gate matrices g = RY(p2)@RZ(p1)@RY(p0)
// into d_ws as 8 floats each: [g00r,g00i, g01r,g01i, g10r,g10i, g11r,g11i].
// Sample-independent, so done once per launch (ws is re-poisoned each call).
// ---------------------------------------------------------------------------
__global__ void make_gates(const float* __restrict__ params, float* __restrict__ gates) {
    int id = threadIdx.x;
    if (id >= NL * NQ) return;
    float p0 = params[id * 3 + 0];
    float p1 = params[id * 3 + 1];
    float p2 = params[id * 3 + 2];
    float c0 = cosf(0.5f * p0), s0 = sinf(0.5f * p0);
    float ch = cosf(0.5f * p1), sh = sinf(0.5f * p1);
    float c2 = cosf(0.5f * p2), s2 = sinf(0.5f * p2);
    // p = exp(-i p1/2) = ch - i sh ; q = conj(p) = ch + i sh
    float pr = ch, pi = -sh;
    float qr = ch, qi = sh;
    float A = c2 * c0, Bc = s2 * s0, Cc = c2 * s0, D = s2 * c0;
    float* g = gates + id * 8;
    g[0] = A * pr - Bc * qr;  g[1] = A * pi - Bc * qi;   // g00 = c2*p*c0 - s2*q*s0
    g[2] = -Cc * pr - D * qr; g[3] = -Cc * pi - D * qi;  // g01 = -c2*p*s0 - s2*q*c0
    g[4] = D * pr + Cc * qr;  g[5] = D * pi + Cc * qi;   // g10 = s2*p*c0 + c2*q*s0
    g[6] = -Bc * pr + A * qr; g[7] = -Bc * pi + A * qi;  // g11 = -s2*p*s0 + c2*q*c0
}

// Apply SU(2)-ish complex 2x2 gate on register bit BBIT of the 16-amp/thread
// register file. g points at 8 floats in LDS.
template <int BBIT>
__device__ __forceinline__ void apply_gate(float2 (&st)[16], const float* __restrict__ g) {
    float4 gA = *(const float4*)(g);       // g00, g01
    float4 gB = *(const float4*)(g + 4);   // g10, g11
#pragma unroll
    for (int k = 0; k < 8; ++k) {
        const int lo = ((k >> BBIT) << (BBIT + 1)) | (k & ((1 << BBIT) - 1));
        const int hi = lo | (1 << BBIT);
        float2 a0 = st[lo], a1 = st[hi];
        float2 n0, n1;
        n0.x = fmaf(gA.x, a0.x, fmaf(-gA.y, a0.y, fmaf(gA.z, a1.x, -gA.w * a1.y)));
        n0.y = fmaf(gA.x, a0.y, fmaf(gA.y, a0.x, fmaf(gA.z, a1.y, gA.w * a1.x)));
        n1.x = fmaf(gB.x, a0.x, fmaf(-gB.y, a0.y, fmaf(gB.z, a1.x, -gB.w * a1.y)));
        n1.y = fmaf(gB.x, a0.y, fmaf(gB.y, a0.x, fmaf(gB.z, a1.y, gB.w * a1.x)));
        st[lo] = n0;
        st[hi] = n1;
    }
}

// LDS physical float2 slot for logical state index idx, with XOR swizzle on
// 16B chunks to keep all transpose access patterns bank-balanced:
//   P(idx) = idx ^ (((idx >> 4) & 7) << 1)
// Bit 0 untouched -> consecutive even/odd pairs stay 16B-contiguous (float4-able).

__launch_bounds__(NTHREADS, 4)
__global__ void qsim_kernel(const float* __restrict__ x,
                            const float* __restrict__ gates,
                            const float* __restrict__ head_w,
                            const float* __restrict__ head_b,
                            float* __restrict__ out) {
    __shared__ __align__(16) float2 sbuf[NSTATE];       // 32 KB transpose buffer
    __shared__ __align__(16) float gmat[NL * NQ * 8];   // 1.125 KB gate matrices
    __shared__ float csx[NQ], snx[NQ];
    __shared__ float wred[NTHREADS / 64];

    const int t = threadIdx.x;
    const int b = blockIdx.x;

    for (int j = t; j < NL * NQ * 8; j += NTHREADS) gmat[j] = gates[j];
    if (t < NQ) {
        float xv = 0.5f * x[b * NQ + t];
        csx[t] = cosf(xv);
        snx[t] = sinf(xv);
    }
    __syncthreads();

    // ---- Init: product state from RX encoding, layout L0: idx = t*16 + r ----
    // wire i <-> state bit (11-i); idx bits 11..4 = t bits 7..0; bits 3..0 = r.
    float2 st[16];
    {
        float common = 1.f;
#pragma unroll
        for (int i = 0; i < 8; ++i)
            common *= ((t >> (7 - i)) & 1) ? snx[i] : csx[i];
        int pct = __popc(t);
#pragma unroll
        for (int r = 0; r < 16; ++r) {
            float low = (((r >> 3) & 1) ? snx[8] : csx[8]) *
                        (((r >> 2) & 1) ? snx[9] : csx[9]) *
                        (((r >> 1) & 1) ? snx[10] : csx[10]) *
                        (((r >> 0) & 1) ? snx[11] : csx[11]);
            float mag = common * low;
            int k = (pct + __popc(r)) & 3;  // phase (-i)^k
            float2 a;
            if (k == 0)      a = make_float2(mag, 0.f);
            else if (k == 1) a = make_float2(0.f, -mag);
            else if (k == 2) a = make_float2(-mag, 0.f);
            else             a = make_float2(0.f, mag);
            st[r] = a;
        }
    }

    const int t_hi = t >> 4, t_lo = t & 15;

    for (int l = 0; l < NL; ++l) {
        const int gb = l * NQ * 8;

        // ---- L0 (reg bit bb = state bit bb = wire 11-bb) ----
        apply_gate<0>(st, &gmat[gb + 11 * 8]);
        apply_gate<1>(st, &gmat[gb + 10 * 8]);
        apply_gate<2>(st, &gmat[gb + 9 * 8]);
        apply_gate<3>(st, &gmat[gb + 8 * 8]);

        // ---- Transpose L0 -> L1 ----
        __syncthreads();
#pragma unroll
        for (int k = 0; k < 8; ++k) {
            int kk = k ^ (t & 7);  // swizzled 16B chunk
            ((float4*)sbuf)[t * 8 + kk] =
                make_float4(st[2 * k].x, st[2 * k].y, st[2 * k + 1].x, st[2 * k + 1].y);
        }
        __syncthreads();
#pragma unroll
        for (int r = 0; r < 16; ++r) {
            int idx = (t_hi << 8) | (r << 4) | t_lo;   // L1: reg bit bb = state bit 4+bb
            st[r] = sbuf[idx ^ ((r & 7) << 1)];
        }

        // ---- L1 (reg bit bb = wire 7-bb) ----
        apply_gate<0>(st, &gmat[gb + 7 * 8]);
        apply_gate<1>(st, &gmat[gb + 6 * 8]);
        apply_gate<2>(st, &gmat[gb + 5 * 8]);
        apply_gate<3>(st, &gmat[gb + 4 * 8]);

        // ---- Transpose L1 -> L2 ----
        __syncthreads();
#pragma unroll
        for (int r = 0; r < 16; ++r) {
            int idx = (t_hi << 8) | (r << 4) | t_lo;
            sbuf[idx ^ ((r & 7) << 1)] = st[r];
        }
        __syncthreads();
        {
            int s2 = (t >> 4) & 7;
#pragma unroll
            for (int r = 0; r < 16; ++r) {
                int idx = (r << 8) | t;                // L2: reg bit bb = state bit 8+bb
                st[r] = sbuf[idx ^ (s2 << 1)];
            }
        }

        // ---- L2 (reg bit bb = wire 3-bb) ----
        apply_gate<0>(st, &gmat[gb + 3 * 8]);
        apply_gate<1>(st, &gmat[gb + 2 * 8]);
        apply_gate<2>(st, &gmat[gb + 1 * 8]);
        apply_gate<3>(st, &gmat[gb + 0 * 8]);

        if (l < NL - 1) {
            // ---- Transpose L2 -> L0, folding the CNOT-chain permutation:
            // new_index m = suffix-XOR of idx over bit positions.
            __syncthreads();
#pragma unroll
            for (int r = 0; r < 16; ++r) {
                int idx = (r << 8) | t;
                int m = idx ^ (idx >> 1);
                m ^= m >> 2; m ^= m >> 4; m ^= m >> 8;
                sbuf[m ^ (((m >> 4) & 7) << 1)] = st[r];
            }
            __syncthreads();
#pragma unroll
            for (int k = 0; k < 8; ++k) {
                int kk = k ^ (t & 7);
                float4 v = ((float4*)sbuf)[t * 8 + kk];
                st[2 * k] = make_float2(v.x, v.y);
                st[2 * k + 1] = make_float2(v.z, v.w);
            }
        }
    }

    // ---- Measurement: last layer's CNOT permutation folded in analytically.
    // out[b] = sum_idx |amp|^2 * wsum(perm(idx)) + bias,
    // wsum(m) = sum_i (bit_{11-i}(m) ? -w_i : +w_i)
    float wv[NQ];
#pragma unroll
    for (int i = 0; i < NQ; ++i) wv[i] = head_w[i];

    float acc = 0.f;
#pragma unroll
    for (int r = 0; r < 16; ++r) {
        int idx = (r << 8) | t;
        int m = idx ^ (idx >> 1);
        m ^= m >> 2; m ^= m >> 4; m ^= m >> 8;
        float p2v = fmaf(st[r].x, st[r].x, st[r].y * st[r].y);
        float ws = 0.f;
#pragma unroll
        for (int i = 0; i < NQ; ++i)
            ws += ((m >> (11 - i)) & 1) ? -wv[i] : wv[i];
        acc = fmaf(p2v, ws, acc);
    }
#pragma unroll
    for (int off = 32; off >= 1; off >>= 1) acc += __shfl_xor(acc, off, 64);
    if ((t & 63) == 0) wred[t >> 6] = acc;
    __syncthreads();
    if (t == 0) out[b] = wred[0] + wred[1] + wred[2] + wred[3] + head_b[0];
}

extern "C" void kernel_launch(void* const* d_in, const int* in_sizes, int n_in,
                              void* d_out, int out_size, void* d_ws, size_t ws_size,
                              hipStream_t stream) {
    const float* x = (const float*)d_in[0];
    const float* params = (const float*)d_in[1];
    const float* head_w = (const float*)d_in[2];
    const float* head_b = (const float*)d_in[3];
    float* out = (float*)d_out;
    float* gates = (float*)d_ws;  // 288 floats
    int B = in_sizes[0] / NQ;

    hipLaunchKernelGGL(make_gates, dim3(1), dim3(64), 0, stream, params, gates);
    hipLaunchKernelGGL(qsim_kernel, dim3(B), dim3(NTHREADS), 0, stream,
                       x, gates, head_w, head_b, out);
}